// Round 12
// baseline (177.496 us; speedup 1.0000x reference)
//
#include <hip/hip_runtime.h>
#include <hip/hip_fp16.h>

// SAGEConv: agg = segment_sum(x[src]*w, dst); out = agg@W_l + b_l + x@W_r + b_r;
// out /= max(sum|out|, 1e-12) row-wise.  N=100000, E=1600000, D=128.
//
// R12: linear MFMA kernel now reads B-fragments (wt) DIRECTLY from global
// (wt = 64KB, L2-resident for all 1563 blocks) instead of staging w_s in
// LDS. LDS/block 52->17.4KB => residency 3->~7 blocks/CU; w_s staging
// loop + its barrier pressure gone. a_s (streamed, single-use) stays in
// LDS. Rest identical to R11 (gather at its L3 service plateau: 60.7us,
// FETCH 188MB = 8-XCD replication floor).

static constexpr int D = 128;
static constexpr int CBITS = 6;     // nodes per bucket = 64
static constexpr int CSZ = 1 << CBITS;
static constexpr int NB = 2048;     // coarse buckets (8KB LDS hist)
static constexpr int NPART = 256;   // partition blocks

typedef _Float16 half8 __attribute__((ext_vector_type(8)));
typedef float f32x4 __attribute__((ext_vector_type(4)));

// ---------- prep: coarse histogram + (optional) x->fp16 + W transpose ----------
__global__ __launch_bounds__(256) void prep(
    const int* __restrict__ edst, int* __restrict__ bhist, int E, int chunk,
    const float4* __restrict__ x4, __half2* __restrict__ xh2, int n4,
    const float* __restrict__ Wl, const float* __restrict__ Wr,
    __half* __restrict__ wt, int do_cvt)
{
    __shared__ int hist[NB];
    const int b = blockIdx.x;
    const int tid = threadIdx.x;
    if (b < NPART) {
        for (int t = tid; t < NB; t += 256) hist[t] = 0;
        __syncthreads();
        const int beg = b * chunk;
        const int end = min(E, beg + chunk);
        int e = beg + tid;
        for (; e + 3 * 256 < end; e += 4 * 256) {
            const int d0 = edst[e];
            const int d1 = edst[e + 256];
            const int d2 = edst[e + 512];
            const int d3 = edst[e + 768];
            atomicAdd(&hist[d0 >> CBITS], 1);
            atomicAdd(&hist[d1 >> CBITS], 1);
            atomicAdd(&hist[d2 >> CBITS], 1);
            atomicAdd(&hist[d3 >> CBITS], 1);
        }
        for (; e < end; e += 256)
            atomicAdd(&hist[edst[e] >> CBITS], 1);
        __syncthreads();
        for (int t = tid; t < NB; t += 256)
            bhist[(size_t)b * NB + t] = hist[t];
    } else if (do_cvt) {
        const int cb = b - NPART;
        if (cb < 1024) {
            int i = cb * 256 + tid;
            const int stride = 1024 * 256;
            for (; i < n4; i += stride) {
                float4 v = x4[i];
                xh2[2 * i + 0] = __floats2half2_rn(v.x, v.y);
                xh2[2 * i + 1] = __floats2half2_rn(v.z, v.w);
            }
        } else {
            const int idx = (cb - 1024) * 256 + tid;
            if (idx < 128 * 256) {
                const int c = idx >> 8;
                const int k = idx & 255;
                const float v = (k < 128) ? Wl[(size_t)k * D + c]
                                          : Wr[(size_t)(k - 128) * D + c];
                wt[(size_t)c * 256 + k] = __float2half(v);
            }
        }
    }
}

// grid 32 x 64: one bucket per thread; scan its NPART per-block counts into
// relative bases (batched 8-wide -> latency pipelines); totals to ctot.
__global__ __launch_bounds__(64) void bucket_scan(
    int* __restrict__ bhist, int* __restrict__ ctot)
{
    const int t = blockIdx.x * 64 + threadIdx.x;   // bucket 0..NB-1
    int run = 0;
    for (int b = 0; b < NPART; b += 8) {
        int v[8];
#pragma unroll
        for (int i = 0; i < 8; ++i)
            v[i] = bhist[(size_t)(b + i) * NB + t];
#pragma unroll
        for (int i = 0; i < 8; ++i) {
            const int c = v[i];
            bhist[(size_t)(b + i) * NB + t] = run;   // relative base
            run += c;
        }
    }
    ctot[t] = run;
}

// 1 block x 1024: exclusive scan of NB=2048 totals -> cbase (wave shfl-scan
// + 16-wave combine, 2 barriers); offs[N]=E.
__global__ __launch_bounds__(1024) void coarse_scan(
    const int* __restrict__ ctot, int* __restrict__ cbase,
    int* __restrict__ offs, int N, int E)
{
    __shared__ int wsum[16];
    const int t = threadIdx.x;
    const int lane = t & 63;
    const int wv = t >> 6;
    const int v0 = ctot[2 * t];
    const int v1 = ctot[2 * t + 1];
    const int loc = v0 + v1;
    int xs = loc;                       // inclusive scan within wave
#pragma unroll
    for (int off = 1; off < 64; off <<= 1) {
        const int y = __shfl_up(xs, off, 64);
        if (lane >= off) xs += y;
    }
    if (lane == 63) wsum[wv] = xs;      // wave total
    __syncthreads();
    if (t < 16) {
        const int w = wsum[t];
        int ws = w;
#pragma unroll
        for (int off = 1; off < 16; off <<= 1) {
            const int y = __shfl_up(ws, off, 64);
            if (lane >= off) ws += y;
        }
        wsum[t] = ws - w;               // exclusive wave base
    }
    __syncthreads();
    const int excl = wsum[wv] + xs - loc;
    cbase[2 * t]     = excl;
    cbase[2 * t + 1] = excl + v0;
    if (t == 1023) { cbase[NB] = excl + loc; offs[N] = E; }
}

// partition edges into coarse buckets; pair = (dst_low6<<20 | src, w_bits)
__global__ __launch_bounds__(256) void coarse_partition(
    const int* __restrict__ esrc, const int* __restrict__ edst,
    const float* __restrict__ ew, const int* __restrict__ bhist,
    const int* __restrict__ cbase,
    int2* __restrict__ cpairs, int E, int chunk)
{
    __shared__ int cur[NB];
    for (int t = threadIdx.x; t < NB; t += 256)
        cur[t] = bhist[(size_t)blockIdx.x * NB + t] + cbase[t];  // absolute
    __syncthreads();
    const int beg = blockIdx.x * chunk;
    const int end = min(E, beg + chunk);
    int e = beg + threadIdx.x;
    for (; e + 3 * 256 < end; e += 4 * 256) {
        int d_[4], s_[4]; float w_[4];
#pragma unroll
        for (int i = 0; i < 4; ++i) {
            d_[i] = edst[e + i * 256];
            s_[i] = esrc[e + i * 256];
            w_[i] = ew[e + i * 256];
        }
#pragma unroll
        for (int i = 0; i < 4; ++i) {
            const int pos = atomicAdd(&cur[d_[i] >> CBITS], 1);
            cpairs[pos] = make_int2(((d_[i] & (CSZ - 1)) << 20) | s_[i],
                                    __float_as_int(w_[i]));
        }
    }
    for (; e < end; e += 256) {
        const int d = edst[e];
        const int pos = atomicAdd(&cur[d >> CBITS], 1);
        cpairs[pos] = make_int2(((d & (CSZ - 1)) << 20) | esrc[e],
                                __float_as_int(ew[e]));
    }
}

// one block per coarse bucket: 64-bin counting sort (wave-scan) + offs[] write
__global__ __launch_bounds__(256) void fine_sort(
    const int2* __restrict__ cpairs, const int* __restrict__ cbase,
    int* __restrict__ offs, int2* __restrict__ pairs, int N)
{
    __shared__ int hist[CSZ], scn[CSZ], cur[CSZ];
    const int b = blockIdx.x;
    const int t = threadIdx.x;
    const int lane = t & 63;
    const int s0 = cbase[b], s1 = cbase[b + 1];
    if (t < CSZ) hist[t] = 0;
    __syncthreads();
    for (int i = s0 + t; i < s1; i += 256)
        atomicAdd(&hist[(cpairs[i].x >> 20) & (CSZ - 1)], 1);
    __syncthreads();
    if (t < CSZ) {                 // wave 0: 64-lane exclusive scan
        const int v = hist[t];
        int xs = v;
#pragma unroll
        for (int off = 1; off < 64; off <<= 1) {
            const int y = __shfl_up(xs, off, 64);
            if (lane >= off) xs += y;
        }
        const int base = s0 + xs - v;
        scn[t] = base;
        cur[t] = base;
        const int node = (b << CBITS) + t;
        if (node < N) offs[node] = base;
    }
    __syncthreads();
    for (int i = s0 + t; i < s1; i += 256) {
        const int2 p = cpairs[i];
        const int pos = atomicAdd(&cur[(p.x >> 20) & (CSZ - 1)], 1);
        pairs[pos] = make_int2(p.x & 0xFFFFF, p.y);
    }
}

// ---------------- gather-aggregate: one wave per node (R6 variant) ----------
// 64 lanes x half2 (4B) per row; 4 edges in flight; dual accumulators.
template <bool FP16X>
__global__ __launch_bounds__(256) void sage_gather(
    const void* __restrict__ xrows,
    const int2* __restrict__ pairs,
    const int* __restrict__ offs,
    void* __restrict__ agg,
    int N)
{
    int node = (blockIdx.x * blockDim.x + threadIdx.x) >> 6;
    const int lane = threadIdx.x & 63;
    if (node >= N) return;
    node = __builtin_amdgcn_readfirstlane(node);
    const int beg = offs[node];
    const int end = offs[node + 1];

    const __half2* __restrict__ xh = (const __half2*)xrows;
    const float2*  __restrict__ xf = (const float2*)xrows;

    float ax0 = 0.f, ay0 = 0.f, ax1 = 0.f, ay1 = 0.f;
    int k = beg;
    for (; k + 4 <= end; k += 4) {
        const int2 p0 = pairs[k + 0];   // uniform addr -> scalar loads
        const int2 p1 = pairs[k + 1];
        const int2 p2 = pairs[k + 2];
        const int2 p3 = pairs[k + 3];
        float2 v0, v1, v2, v3;
        if (FP16X) {
            v0 = __half22float2(xh[(size_t)p0.x * 64 + lane]);
            v1 = __half22float2(xh[(size_t)p1.x * 64 + lane]);
            v2 = __half22float2(xh[(size_t)p2.x * 64 + lane]);
            v3 = __half22float2(xh[(size_t)p3.x * 64 + lane]);
        } else {
            v0 = xf[(size_t)p0.x * 64 + lane];
            v1 = xf[(size_t)p1.x * 64 + lane];
            v2 = xf[(size_t)p2.x * 64 + lane];
            v3 = xf[(size_t)p3.x * 64 + lane];
        }
        const float w0 = __int_as_float(p0.y), w1 = __int_as_float(p1.y);
        const float w2 = __int_as_float(p2.y), w3 = __int_as_float(p3.y);
        ax0 = fmaf(v0.x, w0, ax0); ay0 = fmaf(v0.y, w0, ay0);
        ax1 = fmaf(v1.x, w1, ax1); ay1 = fmaf(v1.y, w1, ay1);
        ax0 = fmaf(v2.x, w2, ax0); ay0 = fmaf(v2.y, w2, ay0);
        ax1 = fmaf(v3.x, w3, ax1); ay1 = fmaf(v3.y, w3, ay1);
    }
    for (; k < end; ++k) {
        const int2 p = pairs[k];
        const float w = __int_as_float(p.y);
        float2 v;
        if (FP16X) v = __half22float2(xh[(size_t)p.x * 64 + lane]);
        else       v = xf[(size_t)p.x * 64 + lane];
        ax0 = fmaf(v.x, w, ax0); ay0 = fmaf(v.y, w, ay0);
    }
    const float ax = ax0 + ax1;
    const float ay = ay0 + ay1;
    if (FP16X) {
        ((__half2*)agg)[(size_t)node * 64 + lane] = __floats2half2_rn(ax, ay);
    } else {
        ((float2*)agg)[(size_t)node * 64 + lane] = make_float2(ax, ay);
    }
}

// ---------------- fallback atomic scatter (ws too small) ----------------
__global__ __launch_bounds__(256) void sage_scatter(
    const float* __restrict__ x,
    const int* __restrict__ esrc,
    const int* __restrict__ edst,
    const float* __restrict__ ew,
    float* agg, int E)
{
    const int lane = threadIdx.x & 63;
    const int warp = (blockIdx.x * blockDim.x + threadIdx.x) >> 6;
    const int nwarps = (gridDim.x * blockDim.x) >> 6;
    const float2* __restrict__ x2 = reinterpret_cast<const float2*>(x);
    for (int e = warp; e < E; e += nwarps) {
        const int s = esrc[e];
        const int d = edst[e];
        const float w = ew[e];
        const float2 xv = x2[s * 64 + lane];
        atomicAdd(&agg[d * D + lane * 2 + 0], xv.x * w);
        atomicAdd(&agg[d * D + lane * 2 + 1], xv.y * w);
    }
}

// ------------- MFMA fused linear(l)+linear(r)+bias+L1-normalize -------------
// R12: B-fragments read directly from global wt (64KB, L2-resident);
// only a_s in LDS (17.4KB) -> ~7 blocks/CU residency.
__global__ __launch_bounds__(256) void sage_linear_norm_mfma(
    const __half* __restrict__ aggh,   // [N][128]
    const __half* __restrict__ xh,     // [N][128]
    const __half* __restrict__ wt,     // [128 cols][256 k]
    const float* __restrict__ bl,
    const float* __restrict__ br,
    float* __restrict__ out,
    int N)
{
    __shared__ __half a_s[64][136];
    const int tid = threadIdx.x;
    const int bn = blockIdx.x * 64;
    const int wv = tid >> 6;     // wave -> row group
    const int l  = tid & 63;
    const int lr = l & 15;       // fragment row/col
    const int lq = l >> 4;       // quarter -> k-subrange / C row group

    f32x4 acc[8];
#pragma unroll
    for (int t = 0; t < 8; ++t) acc[t] = f32x4{0.f, 0.f, 0.f, 0.f};

    const int ar  = tid >> 2;          // A staging: row 0..63
    const int as  = (tid & 3) * 32;    // A staging: 64B offset

#pragma unroll
    for (int c = 0; c < 2; ++c) {
        const __half* __restrict__ A = c ? xh : aggh;
        __syncthreads();   // previous chunk consumed
        {
            const int gn = bn + ar;
            half8 v0 = {}, v1 = {}, v2 = {}, v3 = {};
            if (gn < N) {
                const half8* src = reinterpret_cast<const half8*>(&A[(size_t)gn * D + as]);
                v0 = src[0]; v1 = src[1]; v2 = src[2]; v3 = src[3];
            }
            half8* dst = reinterpret_cast<half8*>(&a_s[ar][as]);
            dst[0] = v0; dst[1] = v1; dst[2] = v2; dst[3] = v3;
        }
        __syncthreads();

#pragma unroll
        for (int ks = 0; ks < 4; ++ks) {
            const int k0 = ks * 32 + lq * 8;
            const half8 af = *reinterpret_cast<const half8*>(&a_s[wv * 16 + lr][k0]);
            const __half* __restrict__ wrow = &wt[(size_t)lr * 256 + c * 128 + k0];
#pragma unroll
            for (int t = 0; t < 8; ++t) {
                // col index = t*16+lr; row stride 256 halves (512B), 16B aligned
                const half8 bf = *reinterpret_cast<const half8*>(&wrow[(size_t)t * 16 * 256]);
                acc[t] = __builtin_amdgcn_mfma_f32_16x16x32_f16(af, bf, acc[t], 0, 0, 0);
            }
        }
    }

    float bias[8];
#pragma unroll
    for (int t = 0; t < 8; ++t) {
        const int cidx = t * 16 + lr;
        bias[t] = bl[cidx] + br[cidx];
    }
    float v[8][4];
    float s0 = 0.f, s1 = 0.f, s2 = 0.f, s3 = 0.f;
#pragma unroll
    for (int t = 0; t < 8; ++t) {
        v[t][0] = acc[t][0] + bias[t];
        v[t][1] = acc[t][1] + bias[t];
        v[t][2] = acc[t][2] + bias[t];
        v[t][3] = acc[t][3] + bias[t];
        s0 += fabsf(v[t][0]); s1 += fabsf(v[t][1]);
        s2 += fabsf(v[t][2]); s3 += fabsf(v[t][3]);
    }
#pragma unroll
    for (int m = 1; m < 16; m <<= 1) {
        s0 += __shfl_xor(s0, m, 64);
        s1 += __shfl_xor(s1, m, 64);
        s2 += __shfl_xor(s2, m, 64);
        s3 += __shfl_xor(s3, m, 64);
    }
    const float r0 = 1.0f / fmaxf(s0, 1e-12f);
    const float r1 = 1.0f / fmaxf(s1, 1e-12f);
    const float r2 = 1.0f / fmaxf(s2, 1e-12f);
    const float r3 = 1.0f / fmaxf(s3, 1e-12f);

    const int nd0 = bn + wv * 16 + lq * 4;
#pragma unroll
    for (int r = 0; r < 4; ++r) {
        const int nd = nd0 + r;
        if (nd < N) {
            const float ri = (r == 0) ? r0 : (r == 1) ? r1 : (r == 2) ? r2 : r3;
#pragma unroll
            for (int t = 0; t < 8; ++t)
                out[(size_t)nd * D + t * 16 + lr] = v[t][r] * ri;
        }
    }
}

// ------------- fp32 fallback linear (tier B/C) -------------
__global__ __launch_bounds__(256) void sage_linear_norm(
    const float* agg, const float* __restrict__ x,
    const float* __restrict__ Wl, const float* __restrict__ bl,
    const float* __restrict__ Wr, const float* __restrict__ br,
    float* out, int N)
{
    __shared__ float a_s[64][68];
    __shared__ float w_s[64][132];
    const int tid = threadIdx.x;
    const int jg = tid & 31;
    const int ng = tid >> 5;
    const int bn = blockIdx.x * 64;

    float acc[8][4];
#pragma unroll
    for (int i = 0; i < 8; ++i) {
        acc[i][0] = 0.f; acc[i][1] = 0.f; acc[i][2] = 0.f; acc[i][3] = 0.f;
    }
    const int sn  = tid >> 2;
    const int skb = (tid & 3) << 4;
    const int wr  = tid >> 5;
    const int wc  = (tid & 31) << 2;

    for (int c = 0; c < 4; ++c) {
        const float* A = (c < 2) ? agg : x;
        const float* __restrict__ W = (c < 2) ? Wl : Wr;
        const int kb = (c & 1) << 6;
        __syncthreads();
        const int gn = bn + sn;
#pragma unroll
        for (int it = 0; it < 4; ++it) {
            float4 vv = make_float4(0.f, 0.f, 0.f, 0.f);
            if (gn < N)
                vv = *reinterpret_cast<const float4*>(&A[(size_t)gn * D + kb + skb + it * 4]);
            *reinterpret_cast<float4*>(&a_s[sn][skb + it * 4]) = vv;
        }
#pragma unroll
        for (int it = 0; it < 8; ++it) {
            const int row = it * 8 + wr;
            const float4 vv = *reinterpret_cast<const float4*>(&W[(size_t)(kb + row) * D + wc]);
            *reinterpret_cast<float4*>(&w_s[row][wc]) = vv;
        }
        __syncthreads();
#pragma unroll 4
        for (int kk = 0; kk < 64; kk += 4) {
            const float4 w0 = *reinterpret_cast<const float4*>(&w_s[kk + 0][jg << 2]);
            const float4 w1 = *reinterpret_cast<const float4*>(&w_s[kk + 1][jg << 2]);
            const float4 w2 = *reinterpret_cast<const float4*>(&w_s[kk + 2][jg << 2]);
            const float4 w3 = *reinterpret_cast<const float4*>(&w_s[kk + 3][jg << 2]);
#pragma unroll
            for (int i = 0; i < 8; ++i) {
                const float4 av = *reinterpret_cast<const float4*>(&a_s[(ng << 3) + i][kk]);
                acc[i][0] = fmaf(av.w, w3.x, fmaf(av.z, w2.x, fmaf(av.y, w1.x, fmaf(av.x, w0.x, acc[i][0]))));
                acc[i][1] = fmaf(av.w, w3.y, fmaf(av.z, w2.y, fmaf(av.y, w1.y, fmaf(av.x, w0.y, acc[i][1]))));
                acc[i][2] = fmaf(av.w, w3.z, fmaf(av.z, w2.z, fmaf(av.y, w1.z, fmaf(av.x, w0.z, acc[i][2]))));
                acc[i][3] = fmaf(av.w, w3.w, fmaf(av.z, w2.w, fmaf(av.y, w1.w, fmaf(av.x, w0.w, acc[i][3]))));
            }
        }
    }
    const float4 bl4 = *reinterpret_cast<const float4*>(&bl[jg << 2]);
    const float4 br4 = *reinterpret_cast<const float4*>(&br[jg << 2]);
    const float bx = bl4.x + br4.x, by = bl4.y + br4.y,
                bz = bl4.z + br4.z, bw = bl4.w + br4.w;
#pragma unroll
    for (int i = 0; i < 8; ++i) {
        const float v0 = acc[i][0] + bx;
        const float v1 = acc[i][1] + by;
        const float v2 = acc[i][2] + bz;
        const float v3 = acc[i][3] + bw;
        float s = fabsf(v0) + fabsf(v1) + fabsf(v2) + fabsf(v3);
#pragma unroll
        for (int m = 1; m < 32; m <<= 1) s += __shfl_xor(s, m, 64);
        s = fmaxf(s, 1e-12f);
        const float r = 1.0f / s;
        const int n = bn + (ng << 3) + i;
        if (n < N) {
            const float4 o = make_float4(v0 * r, v1 * r, v2 * r, v3 * r);
            *reinterpret_cast<float4*>(&out[(size_t)n * D + (jg << 2)]) = o;
        }
    }
}

extern "C" void kernel_launch(void* const* d_in, const int* in_sizes, int n_in,
                              void* d_out, int out_size, void* d_ws, size_t ws_size,
                              hipStream_t stream) {
    const float* x    = (const float*)d_in[0];
    const int*   esrc = (const int*)  d_in[1];
    const int*   edst = (const int*)  d_in[2];
    const float* ew   = (const float*)d_in[3];
    const float* Wl   = (const float*)d_in[4];
    const float* bl   = (const float*)d_in[5];
    const float* Wr   = (const float*)d_in[6];
    const float* br   = (const float*)d_in[7];
    float* out = (float*)d_out;

    const int N = in_sizes[0] / D;
    const int E = in_sizes[1];

    // ws: bhist[NPART*NB] | ctot[NB] | cbase[NB+1] | offs[N+1] | cpairs[E] |
    //     pairs[E] | xh | aggh | wt
    auto align256 = [](size_t v) { return (v + 255) & ~size_t(255); };
    size_t off_bhist  = 0;
    size_t off_ctot   = align256(off_bhist  + (size_t)NPART * NB * 4);
    size_t off_cbase  = align256(off_ctot   + (size_t)NB * 4);
    size_t off_offs   = align256(off_cbase  + (size_t)(NB + 1) * 4);
    size_t off_cpairs = align256(off_offs   + (size_t)(N + 1) * 4);
    size_t off_pairs  = align256(off_cpairs + (size_t)E * 8);
    size_t off_xh     = align256(off_pairs  + (size_t)E * 8);
    size_t off_aggh   = align256(off_xh     + (size_t)N * D * 2);
    size_t off_wt     = align256(off_aggh   + (size_t)N * D * 2);
    size_t need_b     = off_xh;                        // sorted fp32 path
    size_t need_a     = off_wt + (size_t)256 * D * 2;  // full fp16 MFMA path

    const int nbu = (N + CSZ - 1) >> CBITS;
    const bool fits_meta = (N <= (1 << 20)) && (nbu <= NB);

    if (ws_size >= need_b && fits_meta) {
        char* ws = (char*)d_ws;
        int*  bhist  = (int*) (ws + off_bhist);
        int*  ctot   = (int*) (ws + off_ctot);
        int*  cbase  = (int*) (ws + off_cbase);
        int*  offs   = (int*) (ws + off_offs);
        int2* cpairs = (int2*)(ws + off_cpairs);
        int2* pairs  = (int2*)(ws + off_pairs);
        __half2* xh  = (__half2*)(ws + off_xh);
        __half*  agh = (__half*)(ws + off_aggh);
        __half*  wt  = (__half*)(ws + off_wt);

        const bool mfma = (ws_size >= need_a);
        const int chunk = (E + NPART - 1) / NPART;

        const int prep_grid = NPART + (mfma ? (1024 + 128) : 0);
        prep<<<prep_grid, 256, 0, stream>>>(edst, bhist, E, chunk,
                                            (const float4*)x, xh, N * (D / 4),
                                            Wl, Wr, wt, mfma ? 1 : 0);
        bucket_scan<<<NB / 64, 64, 0, stream>>>(bhist, ctot);
        coarse_scan<<<1, 1024, 0, stream>>>(ctot, cbase, offs, N, E);
        coarse_partition<<<NPART, 256, 0, stream>>>(esrc, edst, ew, bhist, cbase,
                                                    cpairs, E, chunk);
        fine_sort<<<nbu, 256, 0, stream>>>(cpairs, cbase, offs, pairs, N);

        const int gb = (N * 64 + 255) / 256;   // one wave per node
        const int nb = (N + 63) / 64;
        if (mfma) {
            sage_gather<true ><<<gb, 256, 0, stream>>>(xh, pairs, offs, agh, N);
            sage_linear_norm_mfma<<<nb, 256, 0, stream>>>(agh, (const __half*)xh, wt,
                                                          bl, br, out, N);
        } else {
            sage_gather<false><<<gb, 256, 0, stream>>>(x, pairs, offs, out, N);
            sage_linear_norm<<<nb, 256, 0, stream>>>(out, x, Wl, bl, Wr, br, out, N);
        }
    } else {
        hipMemsetAsync(out, 0, (size_t)N * D * sizeof(float), stream);
        sage_scatter<<<2048, 256, 0, stream>>>(x, esrc, edst, ew, out, E);
        const int nb = (N + 63) / 64;
        sage_linear_norm<<<nb, 256, 0, stream>>>(out, x, Wl, bl, Wr, br, out, N);
    }
}

// Round 13
// 145.851 us; speedup vs baseline: 1.2170x; 1.2170x over previous
//
#include <hip/hip_runtime.h>
#include <hip/hip_fp16.h>

// SAGEConv: agg = segment_sum(x[src]*w, dst); out = agg@W_l + b_l + x@W_r + b_r;
// out /= max(sum|out|, 1e-12) row-wise.  N=100000, E=1600000, D=128.
//
// R13: exact revert to R11 (best measured: 146.2us). R12's direct-global
// B-fragment experiment regressed (63.5us linear, L2-latency-serialized;
// MfmaUtil 3.8%) -> w_s LDS staging restored. Pipeline:
// prep(count||cvt||wt) -> bucket_scan -> coarse_scan(shfl) -> partition ->
// fine_sort(64-bin wave-scan) -> gather(one wave/node, half2, 4-deep MLP)
// -> MFMA linear+L1norm (a_s+w_s in LDS).
// Measured floors: gather 60.7us = L3 random-256B-row service plateau,
// FETCH 188MB = 8-XCD x 25.6MB replication floor. Fusions (R7/R9/R12)
// all net-negative; sort chain within ~2x of streaming floors.

static constexpr int D = 128;
static constexpr int CBITS = 6;     // nodes per bucket = 64
static constexpr int CSZ = 1 << CBITS;
static constexpr int NB = 2048;     // coarse buckets (8KB LDS hist)
static constexpr int NPART = 256;   // partition blocks

typedef _Float16 half8 __attribute__((ext_vector_type(8)));
typedef float f32x4 __attribute__((ext_vector_type(4)));

// ---------- prep: coarse histogram + (optional) x->fp16 + W transpose ----------
__global__ __launch_bounds__(256) void prep(
    const int* __restrict__ edst, int* __restrict__ bhist, int E, int chunk,
    const float4* __restrict__ x4, __half2* __restrict__ xh2, int n4,
    const float* __restrict__ Wl, const float* __restrict__ Wr,
    __half* __restrict__ wt, int do_cvt)
{
    __shared__ int hist[NB];
    const int b = blockIdx.x;
    const int tid = threadIdx.x;
    if (b < NPART) {
        for (int t = tid; t < NB; t += 256) hist[t] = 0;
        __syncthreads();
        const int beg = b * chunk;
        const int end = min(E, beg + chunk);
        int e = beg + tid;
        for (; e + 3 * 256 < end; e += 4 * 256) {
            const int d0 = edst[e];
            const int d1 = edst[e + 256];
            const int d2 = edst[e + 512];
            const int d3 = edst[e + 768];
            atomicAdd(&hist[d0 >> CBITS], 1);
            atomicAdd(&hist[d1 >> CBITS], 1);
            atomicAdd(&hist[d2 >> CBITS], 1);
            atomicAdd(&hist[d3 >> CBITS], 1);
        }
        for (; e < end; e += 256)
            atomicAdd(&hist[edst[e] >> CBITS], 1);
        __syncthreads();
        for (int t = tid; t < NB; t += 256)
            bhist[(size_t)b * NB + t] = hist[t];
    } else if (do_cvt) {
        const int cb = b - NPART;
        if (cb < 1024) {
            int i = cb * 256 + tid;
            const int stride = 1024 * 256;
            for (; i < n4; i += stride) {
                float4 v = x4[i];
                xh2[2 * i + 0] = __floats2half2_rn(v.x, v.y);
                xh2[2 * i + 1] = __floats2half2_rn(v.z, v.w);
            }
        } else {
            const int idx = (cb - 1024) * 256 + tid;
            if (idx < 128 * 256) {
                const int c = idx >> 8;
                const int k = idx & 255;
                const float v = (k < 128) ? Wl[(size_t)k * D + c]
                                          : Wr[(size_t)(k - 128) * D + c];
                wt[(size_t)c * 256 + k] = __float2half(v);
            }
        }
    }
}

// grid 32 x 64: one bucket per thread; scan its NPART per-block counts into
// relative bases (batched 8-wide -> latency pipelines); totals to ctot.
__global__ __launch_bounds__(64) void bucket_scan(
    int* __restrict__ bhist, int* __restrict__ ctot)
{
    const int t = blockIdx.x * 64 + threadIdx.x;   // bucket 0..NB-1
    int run = 0;
    for (int b = 0; b < NPART; b += 8) {
        int v[8];
#pragma unroll
        for (int i = 0; i < 8; ++i)
            v[i] = bhist[(size_t)(b + i) * NB + t];
#pragma unroll
        for (int i = 0; i < 8; ++i) {
            const int c = v[i];
            bhist[(size_t)(b + i) * NB + t] = run;   // relative base
            run += c;
        }
    }
    ctot[t] = run;
}

// 1 block x 1024: exclusive scan of NB=2048 totals -> cbase (wave shfl-scan
// + 16-wave combine, 2 barriers); offs[N]=E.
__global__ __launch_bounds__(1024) void coarse_scan(
    const int* __restrict__ ctot, int* __restrict__ cbase,
    int* __restrict__ offs, int N, int E)
{
    __shared__ int wsum[16];
    const int t = threadIdx.x;
    const int lane = t & 63;
    const int wv = t >> 6;
    const int v0 = ctot[2 * t];
    const int v1 = ctot[2 * t + 1];
    const int loc = v0 + v1;
    int xs = loc;                       // inclusive scan within wave
#pragma unroll
    for (int off = 1; off < 64; off <<= 1) {
        const int y = __shfl_up(xs, off, 64);
        if (lane >= off) xs += y;
    }
    if (lane == 63) wsum[wv] = xs;      // wave total
    __syncthreads();
    if (t < 16) {
        const int w = wsum[t];
        int ws = w;
#pragma unroll
        for (int off = 1; off < 16; off <<= 1) {
            const int y = __shfl_up(ws, off, 64);
            if (lane >= off) ws += y;
        }
        wsum[t] = ws - w;               // exclusive wave base
    }
    __syncthreads();
    const int excl = wsum[wv] + xs - loc;
    cbase[2 * t]     = excl;
    cbase[2 * t + 1] = excl + v0;
    if (t == 1023) { cbase[NB] = excl + loc; offs[N] = E; }
}

// partition edges into coarse buckets; pair = (dst_low6<<20 | src, w_bits)
__global__ __launch_bounds__(256) void coarse_partition(
    const int* __restrict__ esrc, const int* __restrict__ edst,
    const float* __restrict__ ew, const int* __restrict__ bhist,
    const int* __restrict__ cbase,
    int2* __restrict__ cpairs, int E, int chunk)
{
    __shared__ int cur[NB];
    for (int t = threadIdx.x; t < NB; t += 256)
        cur[t] = bhist[(size_t)blockIdx.x * NB + t] + cbase[t];  // absolute
    __syncthreads();
    const int beg = blockIdx.x * chunk;
    const int end = min(E, beg + chunk);
    int e = beg + threadIdx.x;
    for (; e + 3 * 256 < end; e += 4 * 256) {
        int d_[4], s_[4]; float w_[4];
#pragma unroll
        for (int i = 0; i < 4; ++i) {
            d_[i] = edst[e + i * 256];
            s_[i] = esrc[e + i * 256];
            w_[i] = ew[e + i * 256];
        }
#pragma unroll
        for (int i = 0; i < 4; ++i) {
            const int pos = atomicAdd(&cur[d_[i] >> CBITS], 1);
            cpairs[pos] = make_int2(((d_[i] & (CSZ - 1)) << 20) | s_[i],
                                    __float_as_int(w_[i]));
        }
    }
    for (; e < end; e += 256) {
        const int d = edst[e];
        const int pos = atomicAdd(&cur[d >> CBITS], 1);
        cpairs[pos] = make_int2(((d & (CSZ - 1)) << 20) | esrc[e],
                                __float_as_int(ew[e]));
    }
}

// one block per coarse bucket: 64-bin counting sort (wave-scan) + offs[] write
__global__ __launch_bounds__(256) void fine_sort(
    const int2* __restrict__ cpairs, const int* __restrict__ cbase,
    int* __restrict__ offs, int2* __restrict__ pairs, int N)
{
    __shared__ int hist[CSZ], scn[CSZ], cur[CSZ];
    const int b = blockIdx.x;
    const int t = threadIdx.x;
    const int lane = t & 63;
    const int s0 = cbase[b], s1 = cbase[b + 1];
    if (t < CSZ) hist[t] = 0;
    __syncthreads();
    for (int i = s0 + t; i < s1; i += 256)
        atomicAdd(&hist[(cpairs[i].x >> 20) & (CSZ - 1)], 1);
    __syncthreads();
    if (t < CSZ) {                 // wave 0: 64-lane exclusive scan
        const int v = hist[t];
        int xs = v;
#pragma unroll
        for (int off = 1; off < 64; off <<= 1) {
            const int y = __shfl_up(xs, off, 64);
            if (lane >= off) xs += y;
        }
        const int base = s0 + xs - v;
        scn[t] = base;
        cur[t] = base;
        const int node = (b << CBITS) + t;
        if (node < N) offs[node] = base;
    }
    __syncthreads();
    for (int i = s0 + t; i < s1; i += 256) {
        const int2 p = cpairs[i];
        const int pos = atomicAdd(&cur[(p.x >> 20) & (CSZ - 1)], 1);
        pairs[pos] = make_int2(p.x & 0xFFFFF, p.y);
    }
}

// ---------------- gather-aggregate: one wave per node (R6 variant) ----------
// 64 lanes x half2 (4B) per row; 4 edges in flight; dual accumulators.
template <bool FP16X>
__global__ __launch_bounds__(256) void sage_gather(
    const void* __restrict__ xrows,
    const int2* __restrict__ pairs,
    const int* __restrict__ offs,
    void* __restrict__ agg,
    int N)
{
    int node = (blockIdx.x * blockDim.x + threadIdx.x) >> 6;
    const int lane = threadIdx.x & 63;
    if (node >= N) return;
    node = __builtin_amdgcn_readfirstlane(node);
    const int beg = offs[node];
    const int end = offs[node + 1];

    const __half2* __restrict__ xh = (const __half2*)xrows;
    const float2*  __restrict__ xf = (const float2*)xrows;

    float ax0 = 0.f, ay0 = 0.f, ax1 = 0.f, ay1 = 0.f;
    int k = beg;
    for (; k + 4 <= end; k += 4) {
        const int2 p0 = pairs[k + 0];   // uniform addr -> scalar loads
        const int2 p1 = pairs[k + 1];
        const int2 p2 = pairs[k + 2];
        const int2 p3 = pairs[k + 3];
        float2 v0, v1, v2, v3;
        if (FP16X) {
            v0 = __half22float2(xh[(size_t)p0.x * 64 + lane]);
            v1 = __half22float2(xh[(size_t)p1.x * 64 + lane]);
            v2 = __half22float2(xh[(size_t)p2.x * 64 + lane]);
            v3 = __half22float2(xh[(size_t)p3.x * 64 + lane]);
        } else {
            v0 = xf[(size_t)p0.x * 64 + lane];
            v1 = xf[(size_t)p1.x * 64 + lane];
            v2 = xf[(size_t)p2.x * 64 + lane];
            v3 = xf[(size_t)p3.x * 64 + lane];
        }
        const float w0 = __int_as_float(p0.y), w1 = __int_as_float(p1.y);
        const float w2 = __int_as_float(p2.y), w3 = __int_as_float(p3.y);
        ax0 = fmaf(v0.x, w0, ax0); ay0 = fmaf(v0.y, w0, ay0);
        ax1 = fmaf(v1.x, w1, ax1); ay1 = fmaf(v1.y, w1, ay1);
        ax0 = fmaf(v2.x, w2, ax0); ay0 = fmaf(v2.y, w2, ay0);
        ax1 = fmaf(v3.x, w3, ax1); ay1 = fmaf(v3.y, w3, ay1);
    }
    for (; k < end; ++k) {
        const int2 p = pairs[k];
        const float w = __int_as_float(p.y);
        float2 v;
        if (FP16X) v = __half22float2(xh[(size_t)p.x * 64 + lane]);
        else       v = xf[(size_t)p.x * 64 + lane];
        ax0 = fmaf(v.x, w, ax0); ay0 = fmaf(v.y, w, ay0);
    }
    const float ax = ax0 + ax1;
    const float ay = ay0 + ay1;
    if (FP16X) {
        ((__half2*)agg)[(size_t)node * 64 + lane] = __floats2half2_rn(ax, ay);
    } else {
        ((float2*)agg)[(size_t)node * 64 + lane] = make_float2(ax, ay);
    }
}

// ---------------- fallback atomic scatter (ws too small) ----------------
__global__ __launch_bounds__(256) void sage_scatter(
    const float* __restrict__ x,
    const int* __restrict__ esrc,
    const int* __restrict__ edst,
    const float* __restrict__ ew,
    float* agg, int E)
{
    const int lane = threadIdx.x & 63;
    const int warp = (blockIdx.x * blockDim.x + threadIdx.x) >> 6;
    const int nwarps = (gridDim.x * blockDim.x) >> 6;
    const float2* __restrict__ x2 = reinterpret_cast<const float2*>(x);
    for (int e = warp; e < E; e += nwarps) {
        const int s = esrc[e];
        const int d = edst[e];
        const float w = ew[e];
        const float2 xv = x2[s * 64 + lane];
        atomicAdd(&agg[d * D + lane * 2 + 0], xv.x * w);
        atomicAdd(&agg[d * D + lane * 2 + 1], xv.y * w);
    }
}

// ------------- MFMA fused linear(l)+linear(r)+bias+L1-normalize -------------
__global__ __launch_bounds__(256) void sage_linear_norm_mfma(
    const __half* __restrict__ aggh,   // [N][128]
    const __half* __restrict__ xh,     // [N][128]
    const __half* __restrict__ wt,     // [128 cols][256 k]
    const float* __restrict__ bl,
    const float* __restrict__ br,
    float* __restrict__ out,
    int N)
{
    __shared__ __half a_s[64][136];
    __shared__ __half w_s[128][136];
    const int tid = threadIdx.x;
    const int bn = blockIdx.x * 64;
    const int wv = tid >> 6;     // wave -> row group
    const int l  = tid & 63;
    const int lr = l & 15;       // fragment row/col
    const int lq = l >> 4;       // quarter -> k-subrange / C row group

    f32x4 acc[8];
#pragma unroll
    for (int t = 0; t < 8; ++t) acc[t] = f32x4{0.f, 0.f, 0.f, 0.f};

    const int ar  = tid >> 2;          // A staging: row 0..63
    const int as  = (tid & 3) * 32;    // A staging: 64B offset
    const int wr  = tid >> 1;          // W staging: col-row 0..127
    const int wsg = (tid & 1) * 64;    // W staging: 128B offset

#pragma unroll
    for (int c = 0; c < 2; ++c) {
        const __half* __restrict__ A = c ? xh : aggh;
        __syncthreads();   // previous chunk consumed
        {
            const int gn = bn + ar;
            half8 v0 = {}, v1 = {}, v2 = {}, v3 = {};
            if (gn < N) {
                const half8* src = reinterpret_cast<const half8*>(&A[(size_t)gn * D + as]);
                v0 = src[0]; v1 = src[1]; v2 = src[2]; v3 = src[3];
            }
            half8* dst = reinterpret_cast<half8*>(&a_s[ar][as]);
            dst[0] = v0; dst[1] = v1; dst[2] = v2; dst[3] = v3;
        }
        {
            const half8* src = reinterpret_cast<const half8*>(&wt[(size_t)wr * 256 + c * 128 + wsg]);
            half8* dst = reinterpret_cast<half8*>(&w_s[wr][wsg]);
#pragma unroll
            for (int j = 0; j < 8; ++j) dst[j] = src[j];
        }
        __syncthreads();

#pragma unroll
        for (int ks = 0; ks < 4; ++ks) {
            const int k0 = ks * 32 + lq * 8;
            const half8 af = *reinterpret_cast<const half8*>(&a_s[wv * 16 + lr][k0]);
#pragma unroll
            for (int t = 0; t < 8; ++t) {
                const half8 bf = *reinterpret_cast<const half8*>(&w_s[t * 16 + lr][k0]);
                acc[t] = __builtin_amdgcn_mfma_f32_16x16x32_f16(af, bf, acc[t], 0, 0, 0);
            }
        }
    }

    float bias[8];
#pragma unroll
    for (int t = 0; t < 8; ++t) {
        const int cidx = t * 16 + lr;
        bias[t] = bl[cidx] + br[cidx];
    }
    float v[8][4];
    float s0 = 0.f, s1 = 0.f, s2 = 0.f, s3 = 0.f;
#pragma unroll
    for (int t = 0; t < 8; ++t) {
        v[t][0] = acc[t][0] + bias[t];
        v[t][1] = acc[t][1] + bias[t];
        v[t][2] = acc[t][2] + bias[t];
        v[t][3] = acc[t][3] + bias[t];
        s0 += fabsf(v[t][0]); s1 += fabsf(v[t][1]);
        s2 += fabsf(v[t][2]); s3 += fabsf(v[t][3]);
    }
#pragma unroll
    for (int m = 1; m < 16; m <<= 1) {
        s0 += __shfl_xor(s0, m, 64);
        s1 += __shfl_xor(s1, m, 64);
        s2 += __shfl_xor(s2, m, 64);
        s3 += __shfl_xor(s3, m, 64);
    }
    const float r0 = 1.0f / fmaxf(s0, 1e-12f);
    const float r1 = 1.0f / fmaxf(s1, 1e-12f);
    const float r2 = 1.0f / fmaxf(s2, 1e-12f);
    const float r3 = 1.0f / fmaxf(s3, 1e-12f);

    const int nd0 = bn + wv * 16 + lq * 4;
#pragma unroll
    for (int r = 0; r < 4; ++r) {
        const int nd = nd0 + r;
        if (nd < N) {
            const float ri = (r == 0) ? r0 : (r == 1) ? r1 : (r == 2) ? r2 : r3;
#pragma unroll
            for (int t = 0; t < 8; ++t)
                out[(size_t)nd * D + t * 16 + lr] = v[t][r] * ri;
        }
    }
}

// ------------- fp32 fallback linear (tier B/C) -------------
__global__ __launch_bounds__(256) void sage_linear_norm(
    const float* agg, const float* __restrict__ x,
    const float* __restrict__ Wl, const float* __restrict__ bl,
    const float* __restrict__ Wr, const float* __restrict__ br,
    float* out, int N)
{
    __shared__ float a_s[64][68];
    __shared__ float w_s[64][132];
    const int tid = threadIdx.x;
    const int jg = tid & 31;
    const int ng = tid >> 5;
    const int bn = blockIdx.x * 64;

    float acc[8][4];
#pragma unroll
    for (int i = 0; i < 8; ++i) {
        acc[i][0] = 0.f; acc[i][1] = 0.f; acc[i][2] = 0.f; acc[i][3] = 0.f;
    }
    const int sn  = tid >> 2;
    const int skb = (tid & 3) << 4;
    const int wr  = tid >> 5;
    const int wc  = (tid & 31) << 2;

    for (int c = 0; c < 4; ++c) {
        const float* A = (c < 2) ? agg : x;
        const float* __restrict__ W = (c < 2) ? Wl : Wr;
        const int kb = (c & 1) << 6;
        __syncthreads();
        const int gn = bn + sn;
#pragma unroll
        for (int it = 0; it < 4; ++it) {
            float4 vv = make_float4(0.f, 0.f, 0.f, 0.f);
            if (gn < N)
                vv = *reinterpret_cast<const float4*>(&A[(size_t)gn * D + kb + skb + it * 4]);
            *reinterpret_cast<float4*>(&a_s[sn][skb + it * 4]) = vv;
        }
#pragma unroll
        for (int it = 0; it < 8; ++it) {
            const int row = it * 8 + wr;
            const float4 vv = *reinterpret_cast<const float4*>(&W[(size_t)(kb + row) * D + wc]);
            *reinterpret_cast<float4*>(&w_s[row][wc]) = vv;
        }
        __syncthreads();
#pragma unroll 4
        for (int kk = 0; kk < 64; kk += 4) {
            const float4 w0 = *reinterpret_cast<const float4*>(&w_s[kk + 0][jg << 2]);
            const float4 w1 = *reinterpret_cast<const float4*>(&w_s[kk + 1][jg << 2]);
            const float4 w2 = *reinterpret_cast<const float4*>(&w_s[kk + 2][jg << 2]);
            const float4 w3 = *reinterpret_cast<const float4*>(&w_s[kk + 3][jg << 2]);
#pragma unroll
            for (int i = 0; i < 8; ++i) {
                const float4 av = *reinterpret_cast<const float4*>(&a_s[(ng << 3) + i][kk]);
                acc[i][0] = fmaf(av.w, w3.x, fmaf(av.z, w2.x, fmaf(av.y, w1.x, fmaf(av.x, w0.x, acc[i][0]))));
                acc[i][1] = fmaf(av.w, w3.y, fmaf(av.z, w2.y, fmaf(av.y, w1.y, fmaf(av.x, w0.y, acc[i][1]))));
                acc[i][2] = fmaf(av.w, w3.z, fmaf(av.z, w2.z, fmaf(av.y, w1.z, fmaf(av.x, w0.z, acc[i][2]))));
                acc[i][3] = fmaf(av.w, w3.w, fmaf(av.z, w2.w, fmaf(av.y, w1.w, fmaf(av.x, w0.w, acc[i][3]))));
            }
        }
    }
    const float4 bl4 = *reinterpret_cast<const float4*>(&bl[jg << 2]);
    const float4 br4 = *reinterpret_cast<const float4*>(&br[jg << 2]);
    const float bx = bl4.x + br4.x, by = bl4.y + br4.y,
                bz = bl4.z + br4.z, bw = bl4.w + br4.w;
#pragma unroll
    for (int i = 0; i < 8; ++i) {
        const float v0 = acc[i][0] + bx;
        const float v1 = acc[i][1] + by;
        const float v2 = acc[i][2] + bz;
        const float v3 = acc[i][3] + bw;
        float s = fabsf(v0) + fabsf(v1) + fabsf(v2) + fabsf(v3);
#pragma unroll
        for (int m = 1; m < 32; m <<= 1) s += __shfl_xor(s, m, 64);
        s = fmaxf(s, 1e-12f);
        const float r = 1.0f / s;
        const int n = bn + (ng << 3) + i;
        if (n < N) {
            const float4 o = make_float4(v0 * r, v1 * r, v2 * r, v3 * r);
            *reinterpret_cast<float4*>(&out[(size_t)n * D + (jg << 2)]) = o;
        }
    }
}

extern "C" void kernel_launch(void* const* d_in, const int* in_sizes, int n_in,
                              void* d_out, int out_size, void* d_ws, size_t ws_size,
                              hipStream_t stream) {
    const float* x    = (const float*)d_in[0];
    const int*   esrc = (const int*)  d_in[1];
    const int*   edst = (const int*)  d_in[2];
    const float* ew   = (const float*)d_in[3];
    const float* Wl   = (const float*)d_in[4];
    const float* bl   = (const float*)d_in[5];
    const float* Wr   = (const float*)d_in[6];
    const float* br   = (const float*)d_in[7];
    float* out = (float*)d_out;

    const int N = in_sizes[0] / D;
    const int E = in_sizes[1];

    // ws: bhist[NPART*NB] | ctot[NB] | cbase[NB+1] | offs[N+1] | cpairs[E] |
    //     pairs[E] | xh | aggh | wt
    auto align256 = [](size_t v) { return (v + 255) & ~size_t(255); };
    size_t off_bhist  = 0;
    size_t off_ctot   = align256(off_bhist  + (size_t)NPART * NB * 4);
    size_t off_cbase  = align256(off_ctot   + (size_t)NB * 4);
    size_t off_offs   = align256(off_cbase  + (size_t)(NB + 1) * 4);
    size_t off_cpairs = align256(off_offs   + (size_t)(N + 1) * 4);
    size_t off_pairs  = align256(off_cpairs + (size_t)E * 8);
    size_t off_xh     = align256(off_pairs  + (size_t)E * 8);
    size_t off_aggh   = align256(off_xh     + (size_t)N * D * 2);
    size_t off_wt     = align256(off_aggh   + (size_t)N * D * 2);
    size_t need_b     = off_xh;                        // sorted fp32 path
    size_t need_a     = off_wt + (size_t)256 * D * 2;  // full fp16 MFMA path

    const int nbu = (N + CSZ - 1) >> CBITS;
    const bool fits_meta = (N <= (1 << 20)) && (nbu <= NB);

    if (ws_size >= need_b && fits_meta) {
        char* ws = (char*)d_ws;
        int*  bhist  = (int*) (ws + off_bhist);
        int*  ctot   = (int*) (ws + off_ctot);
        int*  cbase  = (int*) (ws + off_cbase);
        int*  offs   = (int*) (ws + off_offs);
        int2* cpairs = (int2*)(ws + off_cpairs);
        int2* pairs  = (int2*)(ws + off_pairs);
        __half2* xh  = (__half2*)(ws + off_xh);
        __half*  agh = (__half*)(ws + off_aggh);
        __half*  wt  = (__half*)(ws + off_wt);

        const bool mfma = (ws_size >= need_a);
        const int chunk = (E + NPART - 1) / NPART;

        const int prep_grid = NPART + (mfma ? (1024 + 128) : 0);
        prep<<<prep_grid, 256, 0, stream>>>(edst, bhist, E, chunk,
                                            (const float4*)x, xh, N * (D / 4),
                                            Wl, Wr, wt, mfma ? 1 : 0);
        bucket_scan<<<NB / 64, 64, 0, stream>>>(bhist, ctot);
        coarse_scan<<<1, 1024, 0, stream>>>(ctot, cbase, offs, N, E);
        coarse_partition<<<NPART, 256, 0, stream>>>(esrc, edst, ew, bhist, cbase,
                                                    cpairs, E, chunk);
        fine_sort<<<nbu, 256, 0, stream>>>(cpairs, cbase, offs, pairs, N);

        const int gb = (N * 64 + 255) / 256;   // one wave per node
        const int nb = (N + 63) / 64;
        if (mfma) {
            sage_gather<true ><<<gb, 256, 0, stream>>>(xh, pairs, offs, agh, N);
            sage_linear_norm_mfma<<<nb, 256, 0, stream>>>(agh, (const __half*)xh, wt,
                                                          bl, br, out, N);
        } else {
            sage_gather<false><<<gb, 256, 0, stream>>>(x, pairs, offs, out, N);
            sage_linear_norm<<<nb, 256, 0, stream>>>(out, x, Wl, bl, Wr, br, out, N);
        }
    } else {
        hipMemsetAsync(out, 0, (size_t)N * D * sizeof(float), stream);
        sage_scatter<<<2048, 256, 0, stream>>>(x, esrc, edst, ew, out, E);
        const int nb = (N + 63) / 64;
        sage_linear_norm<<<nb, 256, 0, stream>>>(out, x, Wl, bl, Wr, br, out, N);
    }
}